// Round 23
// baseline (208.001 us; speedup 1.0000x reference)
//
#include <hip/hip_runtime.h>
#include <hip/hip_bf16.h>
#include <stdint.h>

#define BATCH 4
#define SEQ 2048
#define DIM 1024
#define HEADS 16
#define HD 64
#define BH (BATCH*HEADS)
#define NQKV (3*DIM)

typedef __attribute__((ext_vector_type(8))) short bf16x8;
typedef __attribute__((ext_vector_type(4))) float f32x4;
typedef __attribute__((ext_vector_type(16))) float f32x16;
typedef __attribute__((ext_vector_type(4))) unsigned u32x4;

#define MFMA16(a,b,c) __builtin_amdgcn_mfma_f32_16x16x32_bf16(a,b,c,0,0,0)
#define MFMA32(a,b,c) __builtin_amdgcn_mfma_f32_32x32x16_bf16(a,b,c,0,0,0)

#if __has_builtin(__builtin_amdgcn_exp2f)
#define EXP2(x) __builtin_amdgcn_exp2f(x)
#else
#define EXP2(x) exp2f(x)
#endif

__device__ inline float bf2f(short s){
    unsigned u = ((unsigned)(unsigned short)s) << 16;
    float f;
    __builtin_memcpy(&f, &u, 4);
    return f;
}
__device__ inline unsigned cvt_pk_bf16(float lo, float hi){
    unsigned r;
    asm("v_cvt_pk_bf16_f32 %0, %1, %2" : "=v"(r) : "v"(lo), "v"(hi));
    return r;
}
__device__ inline short cv1(float f){
    return (short)(cvt_pk_bf16(f, f) & 0xffffu);
}

// ---------------- convert x -> bf16 (vectorized) ----------------
__global__ void conv_bf16(const float* __restrict__ in, short* __restrict__ out, int n4){
    int i = blockIdx.x*blockDim.x + threadIdx.x;
    f32x4 v = *(const f32x4*)&in[(size_t)i*4];
    unsigned lo = cvt_pk_bf16(v[0], v[1]);
    unsigned hi = cvt_pk_bf16(v[2], v[3]);
    unsigned out2[2] = {lo, hi};
    __builtin_memcpy(&out[(size_t)i*4], out2, 8);
}

// ---------------- transpose + convert (R x C f32) -> (C x R bf16) ----------------
__global__ void transpose_conv(const float* __restrict__ in, short* __restrict__ out, int R, int C){
    __shared__ float tile[32][33];
    int c0 = blockIdx.x*32, r0 = blockIdx.y*32;
    int tx = threadIdx.x, ty = threadIdx.y;   // block (32,8)
    #pragma unroll
    for (int dy = 0; dy < 32; dy += 8)
        tile[ty+dy][tx] = in[(size_t)(r0+ty+dy)*C + c0+tx];
    __syncthreads();
    #pragma unroll
    for (int dy = 0; dy < 32; dy += 8)
        out[(size_t)(c0+ty+dy)*R + r0+tx] = cv1(tile[tx][ty+dy]);
}

// ---------------- GEMM 256x128 QKV: dbuf BK=32, counted vmcnt(3), raw barriers ----------------
// T3+T4 minimum form: stage(t+1) issued before compute(t); vmcnt(3) (not 0) lets
// next-tile loads fly across the barrier. LDS = 2*(16K+8K) = 48KB (same as R21).
__global__ __launch_bounds__(512) void gemm_bt2(const short* __restrict__ A, const short* __restrict__ Bt,
                        short* __restrict__ Cout, int M, int N, int K)
{
    __shared__ short As[2][8192];   // [buf][256*32]
    __shared__ short Bs[2][4096];   // [buf][128*32]
    const int t = threadIdx.x;
    const int lane = t & 63, wave = t >> 6;       // 0..7
    const int wr = wave >> 1, wc = wave & 1;      // 4x2 waves, each 64x64
    const int nbn = N >> 7;
    const int cpx = gridDim.x >> 3;
    const int swz = (blockIdx.x & 7) * cpx + (blockIdx.x >> 3);
    const int bm = swz / nbn, bn = swz % nbn;
    const int m0 = bm*256, n0 = bn*128;
    const int l15 = lane & 15, lhi = lane >> 4;

    // per-thread staging geometry (3 loads/stage: 2 A + 1 B)
    const int baseA0 = (wave*64)*8,        offA0 = baseA0 + lane*8;
    const int baseA1 = (512 + wave*64)*8,  offA1 = baseA1 + lane*8;
    const int rowA0 = offA0 >> 5, colA0 = offA0 & 31;
    const int rowA1 = offA1 >> 5, colA1 = offA1 & 31;
    const int baseB = (wave*64)*8,         offB = baseB + lane*8;
    const int rowB = offB >> 5, colB = offB & 31;

#define STAGE2(buf, kc) do { \
    __builtin_amdgcn_global_load_lds( \
        (const __attribute__((address_space(1))) void*)(A + (size_t)(m0+rowA0)*K + (kc) + colA0), \
        (__attribute__((address_space(3))) void*)(&As[buf][baseA0]), 16, 0, 0); \
    __builtin_amdgcn_global_load_lds( \
        (const __attribute__((address_space(1))) void*)(A + (size_t)(m0+rowA1)*K + (kc) + colA1), \
        (__attribute__((address_space(3))) void*)(&As[buf][baseA1]), 16, 0, 0); \
    __builtin_amdgcn_global_load_lds( \
        (const __attribute__((address_space(1))) void*)(Bt + (size_t)(n0+rowB)*K + (kc) + colB), \
        (__attribute__((address_space(3))) void*)(&Bs[buf][baseB]), 16, 0, 0); \
} while(0)

    f32x4 acc[4][4];
    #pragma unroll
    for (int i=0;i<4;i++)
        #pragma unroll
        for (int j=0;j<4;j++) acc[i][j] = (f32x4){0.f,0.f,0.f,0.f};

    STAGE2(0, 0);
    const int nt = K >> 5;
    for (int ti = 0; ti < nt; ++ti) {
        const int cur = ti & 1;
        if (ti + 1 < nt) {
            STAGE2(cur^1, (ti+1) << 5);
            asm volatile("s_waitcnt vmcnt(3)" ::: "memory");  // own tile-ti loads done; next-tile in flight
        } else {
            asm volatile("s_waitcnt vmcnt(0)" ::: "memory");
        }
        __builtin_amdgcn_s_barrier();
        __builtin_amdgcn_sched_barrier(0);

        bf16x8 a[4], b[4];
        #pragma unroll
        for (int i=0;i<4;i++)
            a[i] = *(const bf16x8*)&As[cur][(wr*64 + i*16 + l15)*32 + lhi*8];
        #pragma unroll
        for (int j=0;j<4;j++)
            b[j] = *(const bf16x8*)&Bs[cur][(wc*64 + j*16 + l15)*32 + lhi*8];
        __builtin_amdgcn_s_setprio(1);
        #pragma unroll
        for (int i=0;i<4;i++)
            #pragma unroll
            for (int j=0;j<4;j++)
                acc[i][j] = MFMA16(a[i], b[j], acc[i][j]);
        __builtin_amdgcn_s_setprio(0);

        asm volatile("s_waitcnt lgkmcnt(0)" ::: "memory");  // reads of buf[cur] retired
        __builtin_amdgcn_s_barrier();                       // safe to overwrite next iter
    }
#undef STAGE2

    #pragma unroll
    for (int i=0;i<4;i++)
        #pragma unroll
        for (int j=0;j<4;j++)
            #pragma unroll
            for (int jj=0;jj<4;jj++) {
                int row = m0 + wr*64 + i*16 + lhi*4 + jj;
                int col = n0 + wc*64 + j*16 + l15;
                Cout[(size_t)row*N + col] = cv1(acc[i][j][jj]);
            }
}

// ---------------- out-projection GEMM with FUSED combine in A-staging (R22) ----------------
__global__ __launch_bounds__(256) void gemm_out(const short* __restrict__ obuf,
        const float* __restrict__ lbuf, const short* __restrict__ Bt,
        float* __restrict__ Cout)
{
    const int N = 1024, K = 1024;
    __shared__ short As[2*128*32];
    __shared__ short Bs[2*128*32];
    const int t = threadIdx.x;
    const int lane = t & 63, wave = t >> 6;
    const int wr = wave >> 1, wc = wave & 1;
    const int nbn = 8;
    const int cpx = gridDim.x >> 3;
    const int swz = (blockIdx.x & 7) * cpx + (blockIdx.x >> 3);
    const int bm = swz / nbn, bn = swz % nbn;
    const int m0 = bm*128, n0 = bn*128;
    const int l15 = lane & 15, lhi = lane >> 4;

    f32x4 acc[4][4];
    #pragma unroll
    for (int i=0;i<4;i++)
        #pragma unroll
        for (int j=0;j<4;j++) acc[i][j] = (f32x4){0.f,0.f,0.f,0.f};

    for (int k0 = 0; k0 < K; k0 += 64) {
        #pragma unroll
        for (int kk = 0; kk < 2; ++kk) {
            #pragma unroll
            for (int it = 0; it < 2; ++it) {
                const int loff = (it*256 + wave*64 + lane)*8;
                const int row = loff >> 5, col = loff & 31;
                const int grow = m0 + row;
                const int gcol = k0 + kk*32 + col;
                const int bq = grow >> 11, q = grow & 2047;
                const int h = gcol >> 6, d = gcol & 63;
                const size_t tile = ((size_t)(bq*16 + h) << 6) + (q >> 5);
                const short* op = obuf + tile*4096 + (q & 31)*64 + d;
                bf16x8 a0 = *(const bf16x8*)op;
                bf16x8 a1 = *(const bf16x8*)(op + 2048);
                const float* lb = lbuf + tile*64 + (q & 31);
                float inv = 1.0f / (lb[0] + lb[32]);
                unsigned w[4];
                #pragma unroll
                for (int j=0;j<4;j++)
                    w[j] = cvt_pk_bf16((bf2f(a0[2*j])   + bf2f(a1[2*j]))   * inv,
                                       (bf2f(a0[2*j+1]) + bf2f(a1[2*j+1])) * inv);
                __builtin_memcpy(&As[kk*4096 + loff], w, 16);

                const int base = kk*4096 + (it*256 + wave*64)*8;
                __builtin_amdgcn_global_load_lds(
                    (const __attribute__((address_space(1))) void*)(Bt + (size_t)(n0+row)*K + gcol),
                    (__attribute__((address_space(3))) void*)(Bs + base), 16, 0, 0);
            }
        }
        __syncthreads();
        #pragma unroll
        for (int kk = 0; kk < 2; ++kk) {
            bf16x8 a[4], b[4];
            #pragma unroll
            for (int i=0;i<4;i++)
                a[i] = *(const bf16x8*)&As[kk*4096 + (wr*64 + i*16 + l15)*32 + lhi*8];
            #pragma unroll
            for (int j=0;j<4;j++)
                b[j] = *(const bf16x8*)&Bs[kk*4096 + (wc*64 + j*16 + l15)*32 + lhi*8];
            #pragma unroll
            for (int i=0;i<4;i++)
                #pragma unroll
                for (int j=0;j<4;j++)
                    acc[i][j] = MFMA16(a[i], b[j], acc[i][j]);
        }
        __syncthreads();
    }

    #pragma unroll
    for (int i=0;i<4;i++)
        #pragma unroll
        for (int j=0;j<4;j++)
            #pragma unroll
            for (int jj=0;jj<4;jj++) {
                int row = m0 + wr*64 + i*16 + lhi*4 + jj;
                int col = n0 + wc*64 + j*16 + l15;
                Cout[(size_t)row*N + col] = acc[i][j][jj];
            }
}

// ---------------- RoPE + scatter into MFMA-fragment-packed layouts ----------------
__global__ __launch_bounds__(256) void rope_scatter(const short* __restrict__ qkvb,
                             short* __restrict__ qp, short* __restrict__ kp,
                             short* __restrict__ vp,
                             float* __restrict__ kout, float* __restrict__ vout)
{
    __shared__ short vt[64*72];
    const int t = threadIdx.x;
    const int bh = blockIdx.x >> 5;
    const int sb = blockIdx.x & 31;
    const int b = bh >> 4, h = bh & 15;
    const int s_loc = t >> 2, ic = (t & 3) << 3;
    const int s = (sb << 6) + s_loc;
    const size_t rowbase = ((size_t)(b*SEQ + s))*NQKV + h*HD;

    bf16x8 q1 = *(const bf16x8*)&qkvb[rowbase + ic];
    bf16x8 q2 = *(const bf16x8*)&qkvb[rowbase + ic + 32];
    bf16x8 k1 = *(const bf16x8*)&qkvb[rowbase + DIM + ic];
    bf16x8 k2 = *(const bf16x8*)&qkvb[rowbase + DIM + ic + 32];
    bf16x8 v1 = *(const bf16x8*)&qkvb[rowbase + 2*DIM + ic];
    bf16x8 v2 = *(const bf16x8*)&qkvb[rowbase + 2*DIM + ic + 32];

    const float QS = 0.125f * 1.4426950408889634f;
    float q1s[8], q2s[8], k1f[8], k2f[8], v1f[8], v2f[8];
    #pragma unroll
    for (int j=0;j<8;j++){
        int i = ic + j;
        float inv = exp2f(-(float)i * (13.287712379549449f/32.0f));
        float ang = (float)s * inv;
        float sn, cs;
        sincosf(ang, &sn, &cs);
        float q1f = bf2f(q1[j]), q2f = bf2f(q2[j]);
        float ka = bf2f(k1[j]), kb_ = bf2f(k2[j]);
        float qr1 = q1f*cs - q2f*sn, qr2 = q2f*cs + q1f*sn;
        float kr1 = ka*cs - kb_*sn,  kr2 = kb_*cs + ka*sn;
        q1s[j] = qr1*QS; q2s[j] = qr2*QS;
        k1f[j] = kr1; k2f[j] = kr2;
        v1f[j] = bf2f(v1[j]); v2f[j] = bf2f(v2[j]);
    }
    bf16x8 qo1, qo2, ko1, ko2;
    {
        unsigned w[4];
        #pragma unroll
        for (int j=0;j<4;j++) w[j] = cvt_pk_bf16(q1s[2*j], q1s[2*j+1]);
        __builtin_memcpy(&qo1, w, 16);
        #pragma unroll
        for (int j=0;j<4;j++) w[j] = cvt_pk_bf16(q2s[2*j], q2s[2*j+1]);
        __builtin_memcpy(&qo2, w, 16);
        #pragma unroll
        for (int j=0;j<4;j++) w[j] = cvt_pk_bf16(k1f[2*j], k1f[2*j+1]);
        __builtin_memcpy(&ko1, w, 16);
        #pragma unroll
        for (int j=0;j<4;j++) w[j] = cvt_pk_bf16(k2f[2*j], k2f[2*j+1]);
        __builtin_memcpy(&ko2, w, 16);
    }

    const size_t obase = ((size_t)bh*SEQ + s)*HD;
    #pragma unroll
    for (int j4=0;j4<2;j4++){
        *(f32x4*)&kout[obase+ic+j4*4]    = (f32x4){k1f[j4*4],k1f[j4*4+1],k1f[j4*4+2],k1f[j4*4+3]};
        *(f32x4*)&kout[obase+ic+32+j4*4] = (f32x4){k2f[j4*4],k2f[j4*4+1],k2f[j4*4+2],k2f[j4*4+3]};
        *(f32x4*)&vout[obase+ic+j4*4]    = (f32x4){v1f[j4*4],v1f[j4*4+1],v1f[j4*4+2],v1f[j4*4+3]};
        *(f32x4*)&vout[obase+ic+32+j4*4] = (f32x4){v2f[j4*4],v2f[j4*4+1],v2f[j4*4+2],v2f[j4*4+3]};
    }

    {
        const int tkv = (sb << 1) + (s_loc >> 5);
        const int rlo = s_loc & 31;
        const int g1 = ic >> 3,   i1 = g1 >> 1, H1 = g1 & 1;
        const int g2 = 4+(ic>>3), i2 = g2 >> 1, H2 = g2 & 1;
        const size_t tb = ((size_t)bh*64 + tkv)*4;
        *(bf16x8*)&qp[(tb + i1)*512 + (H1*32 + rlo)*8] = qo1;
        *(bf16x8*)&qp[(tb + i2)*512 + (H2*32 + rlo)*8] = qo2;
        *(bf16x8*)&kp[(tb + i1)*512 + (H1*32 + rlo)*8] = ko1;
        *(bf16x8*)&kp[(tb + i2)*512 + (H2*32 + rlo)*8] = ko2;
    }

    #pragma unroll
    for (int j=0;j<8;j++){
        int i = ic + j;
        vt[i*72 + ((((s_loc>>3) ^ (i&7) ^ (i>>3)) & 7)<<3) + (s_loc&7)] = v1[j];
        int i2 = i + 32;
        vt[i2*72 + ((((s_loc>>3) ^ (i2&7) ^ (i2>>3)) & 7)<<3) + (s_loc&7)] = v2[j];
    }
    __syncthreads();

    const int i_out = t >> 2, g = t & 3;
    const int nn = i_out >> 5, l31v = i_out & 31;
    #pragma unroll
    for (int cc=0; cc<2; ++cc){
        int c = 2*g + cc;
        bf16x8 rv = *(const bf16x8*)&vt[i_out*72 + ((((c) ^ (i_out&7) ^ (i_out>>3)) & 7)<<3)];
        int tkv = (sb << 1) + (c >> 2);
        int m = (c >> 1) & 1, H = c & 1;
        size_t va = ((((size_t)bh*64 + tkv)*2 + nn)*2 + m)*512 + (H*32 + l31v)*8;
        *(bf16x8*)&vp[va] = rv;
    }
}

// ---------------- flash attention, partial (KV-split across blocks, 32x32 MFMA) ----------------
#define ATT_BODY(KU, KP) do { \
    const unsigned sOff = (unsigned)step << 11; \
    { int npos = step + 1; npos = (npos < hi) ? npos : step; \
      const unsigned pOff = (unsigned)npos << 11; \
      _Pragma("unroll") \
      for (int i=0;i<4;i++) \
          KP[i] = *(const bf16x8*)&kbase[pOff + i*512 + lane*8]; } \
    bf16x8 vf[2][2]; \
    _Pragma("unroll") \
    for (int nn=0;nn<2;nn++) \
        _Pragma("unroll") \
        for (int m=0;m<2;m++) \
            vf[nn][m] = *(const bf16x8*)&vbase[sOff + nn*1024 + m*512 + lane*8]; \
    __builtin_amdgcn_s_setprio(1); \
    f32x16 sacc; \
    _Pragma("unroll") \
    for (int rr=0;rr<16;rr++) sacc[rr] = 0.f; \
    _Pragma("unroll") \
    for (int i=0;i<4;i++) \
        sacc = MFMA32(KU[i], qf[i], sacc); \
    __builtin_amdgcn_s_setprio(0); \
    if (step == n-1) { \
        const int kv0 = step << 5; \
        _Pragma("unroll") \
        for (int rr=0;rr<16;rr++){ \
            int kv = kv0 + (rr&3) + 8*(rr>>2) + 4*H; \
            if (kv > q0 + l31) sacc[rr] = -3.0e38f; \
        } \
    } \
    float p[16]; \
    _Pragma("unroll") \
    for (int rr=0;rr<16;rr++) p[rr] = EXP2(sacc[rr]); \
    unsigned W0 = cvt_pk_bf16(p[0],  p[1]); \
    unsigned W1 = cvt_pk_bf16(p[2],  p[3]); \
    unsigned W2 = cvt_pk_bf16(p[4],  p[5]); \
    unsigned W3 = cvt_pk_bf16(p[6],  p[7]); \
    unsigned W4 = cvt_pk_bf16(p[8],  p[9]); \
    unsigned W5 = cvt_pk_bf16(p[10], p[11]); \
    unsigned W6 = cvt_pk_bf16(p[12], p[13]); \
    unsigned W7 = cvt_pk_bf16(p[14], p[15]); \
    asm("v_permlane32_swap_b32 %0, %1" : "+v"(W0), "+v"(W2)); \
    asm("v_permlane32_swap_b32 %0, %1" : "+v"(W1), "+v"(W3)); \
    asm("v_permlane32_swap_b32 %0, %1" : "+v"(W4), "+v"(W6)); \
    asm("v_permlane32_swap_b32 %0, %1" : "+v"(W5), "+v"(W7)); \
    u32x4 paw0 = (u32x4){W0, W1, W2, W3}; \
    u32x4 paw1 = (u32x4){W4, W5, W6, W7}; \
    bf16x8 pa[2]; \
    __builtin_memcpy(&pa[0], &paw0, 16); \
    __builtin_memcpy(&pa[1], &paw1, 16); \
    __builtin_amdgcn_s_setprio(1); \
    _Pragma("unroll") \
    for (int nn=0;nn<2;nn++) \
        _Pragma("unroll") \
        for (int m=0;m<2;m++) \
            o[nn] = MFMA32(pa[m], vf[nn][m], o[nn]); \
    psum = MFMA32(pa[0], onesf, psum); \
    psum = MFMA32(pa[1], onesf, psum); \
    __builtin_amdgcn_s_setprio(0); \
} while(0)

__global__ __launch_bounds__(64) void attn_partial(
        const short* __restrict__ qp, const short* __restrict__ kp,
        const short* __restrict__ vp, short* __restrict__ obuf,
        float* __restrict__ lbuf)
{
    const int lane = threadIdx.x;
    const int wg = blockIdx.x;               // 4096 = 8x * 8bh-hi * 32pp * 2half
    const int x = wg & 7;                    // XCD swizzle
    const int r = wg >> 3;                   // 0..511
    const int half = r & 1;
    const int pp = (r >> 1) & 31;
    const int bh = (x << 3) | (r >> 6);
    const int l31 = lane & 31;
    const int H = lane >> 5;                 // 0 or 1
    const short* kbase = kp + (size_t)bh * 64 * 2048;
    const short* vbase = vp + (size_t)bh * 64 * 2048;
    const short* qbase = qp + (size_t)bh * 64 * 2048;

    bf16x8 onesf;
    #pragma unroll
    for (int j=0;j<8;j++) onesf[j] = (short)0x3F80;   // bf16 1.0

    #pragma unroll 1
    for (int part = 0; part < 2; ++part) {
        const int qt = part ? (63 - pp) : pp;
        const int q0 = qt << 5;
        const int n  = qt + 1;               // total kv32 steps for this tile
        const int mid = (n + 1) >> 1;
        const int lo = half ? mid : 0;
        const int hi = half ? n : mid;

        bf16x8 qf[4];
        #pragma unroll
        for (int i=0;i<4;i++)
            qf[i] = *(const bf16x8*)&qbase[(unsigned)qt*2048 + i*512 + lane*8];

        f32x16 o[2], psum;
        #pragma unroll
        for (int nn=0;nn<2;nn++)
            #pragma unroll
            for (int rr=0;rr<16;rr++) o[nn][rr] = 0.f;
        #pragma unroll
        for (int rr=0;rr<16;rr++) psum[rr] = 0.f;

        if (lo < hi) {
            bf16x8 kfA[4], kfB[4];
            #pragma unroll
            for (int i=0;i<4;i++)
                kfA[i] = *(const bf16x8*)&kbase[(unsigned)lo*2048 + i*512 + lane*8];

            int step = lo;
            while (1) {
                ATT_BODY(kfA, kfB);
                ++step; if (step >= hi) break;
                ATT_BODY(kfB, kfA);
                ++step; if (step >= hi) break;
            }
        }

        short* ob = obuf + (size_t)(((bh << 6) | qt)*2 + half) * 2048;
        #pragma unroll
        for (int nn=0;nn<2;nn++)
            #pragma unroll
            for (int rr=0;rr<16;rr++){
                int qloc = (rr&3) + 8*(rr>>2) + 4*H;
                ob[qloc*64 + nn*32 + l31] = cv1(o[nn][rr]);
            }
        float* lb = lbuf + (size_t)(((bh << 6) | qt)*2 + half) * 32;
        if (l31 == 0) {
            #pragma unroll
            for (int rr=0;rr<16;rr++){
                int qloc = (rr&3) + 8*(rr>>2) + 4*H;
                lb[qloc] = psum[rr];
            }
        }
    }
}
#undef ATT_BODY

extern "C" void kernel_launch(void* const* d_in, const int* in_sizes, int n_in,
                              void* d_out, int out_size, void* d_ws, size_t ws_size,
                              hipStream_t stream) {
    const float* x     = (const float*)d_in[0];
    const float* w_qkv = (const float*)d_in[1];
    const float* w_out = (const float*)d_in[2];
    float* out  = (float*)d_out;
    float* kout = out + (size_t)BATCH*SEQ*DIM;          // 8388608
    float* vout = kout + (size_t)BH*SEQ*HD;             // +8388608

    char* ws = (char*)d_ws;
    short* xb    = (short*)(ws + 0);                    // 16 MB
    short* wqkvT = (short*)(ws + 16777216);             // 6 MB
    short* woutT = (short*)(ws + 23068672);             // 2 MB
    short* qkvb  = (short*)(ws + 25165824);             // 48 MB (8192x3072 bf16)
    short* obuf  = (short*)(ws + 25165824);             // reuses qkvb after rope
    float* lbuf  = (float*)(ws + 25165824 + 33554432);
    short* qp    = (short*)(ws + 75497472);             // 16 MB (packed Q frags)
    short* kp    = (short*)(ws + 92274688);             // 16 MB (packed K frags)
    short* vp    = (short*)(ws + 109051904);            // 16 MB (packed V frags)

    conv_bf16<<<(BATCH*SEQ*DIM)/1024, 256, 0, stream>>>(x, xb, (BATCH*SEQ*DIM)/4);
    transpose_conv<<<dim3(NQKV/32, DIM/32), dim3(32,8), 0, stream>>>(w_qkv, wqkvT, DIM, NQKV);
    transpose_conv<<<dim3(DIM/32, DIM/32), dim3(32,8), 0, stream>>>(w_out, woutT, DIM, DIM);

    gemm_bt2<<<(8192/256)*(NQKV/128), 512, 0, stream>>>(xb, wqkvT, qkvb, 8192, NQKV, DIM);

    rope_scatter<<<BH*(SEQ/64), 256, 0, stream>>>(qkvb, qp, kp, vp, kout, vout);

    attn_partial<<<4096, 64, 0, stream>>>(qp, kp, vp, obuf, lbuf);

    gemm_out<<<(8192/128)*(DIM/128), 256, 0, stream>>>(obuf, lbuf, woutT, out);
}

// Round 24
// 205.559 us; speedup vs baseline: 1.0119x; 1.0119x over previous
//
#include <hip/hip_runtime.h>
#include <hip/hip_bf16.h>
#include <stdint.h>

#define BATCH 4
#define SEQ 2048
#define DIM 1024
#define HEADS 16
#define HD 64
#define BH (BATCH*HEADS)
#define NQKV (3*DIM)

typedef __attribute__((ext_vector_type(8))) short bf16x8;
typedef __attribute__((ext_vector_type(4))) float f32x4;
typedef __attribute__((ext_vector_type(16))) float f32x16;
typedef __attribute__((ext_vector_type(4))) unsigned u32x4;

#define MFMA16(a,b,c) __builtin_amdgcn_mfma_f32_16x16x32_bf16(a,b,c,0,0,0)
#define MFMA32(a,b,c) __builtin_amdgcn_mfma_f32_32x32x16_bf16(a,b,c,0,0,0)

#if __has_builtin(__builtin_amdgcn_exp2f)
#define EXP2(x) __builtin_amdgcn_exp2f(x)
#else
#define EXP2(x) exp2f(x)
#endif

__device__ inline float bf2f(short s){
    unsigned u = ((unsigned)(unsigned short)s) << 16;
    float f;
    __builtin_memcpy(&f, &u, 4);
    return f;
}
__device__ inline unsigned cvt_pk_bf16(float lo, float hi){
    unsigned r;
    asm("v_cvt_pk_bf16_f32 %0, %1, %2" : "=v"(r) : "v"(lo), "v"(hi));
    return r;
}
__device__ inline short cv1(float f){
    return (short)(cvt_pk_bf16(f, f) & 0xffffu);
}

// ---------------- convert x -> bf16 (vectorized) ----------------
__global__ void conv_bf16(const float* __restrict__ in, short* __restrict__ out, int n4){
    int i = blockIdx.x*blockDim.x + threadIdx.x;
    f32x4 v = *(const f32x4*)&in[(size_t)i*4];
    unsigned lo = cvt_pk_bf16(v[0], v[1]);
    unsigned hi = cvt_pk_bf16(v[2], v[3]);
    unsigned out2[2] = {lo, hi};
    __builtin_memcpy(&out[(size_t)i*4], out2, 8);
}

// ---------------- transpose + convert (R x C f32) -> (C x R bf16) ----------------
__global__ void transpose_conv(const float* __restrict__ in, short* __restrict__ out, int R, int C){
    __shared__ float tile[32][33];
    int c0 = blockIdx.x*32, r0 = blockIdx.y*32;
    int tx = threadIdx.x, ty = threadIdx.y;   // block (32,8)
    #pragma unroll
    for (int dy = 0; dy < 32; dy += 8)
        tile[ty+dy][tx] = in[(size_t)(r0+ty+dy)*C + c0+tx];
    __syncthreads();
    #pragma unroll
    for (int dy = 0; dy < 32; dy += 8)
        out[(size_t)(c0+ty+dy)*R + r0+tx] = cv1(tile[tx][ty+dy]);
}

// ---------------- GEMM 256x128 (BK=64, 8 waves, XCD swizzle): QKV projection ----------------
__global__ __launch_bounds__(512) void gemm_bt2(const short* __restrict__ A, const short* __restrict__ Bt,
                        short* __restrict__ Cout, int M, int N, int K)
{
    __shared__ short As[2][8192];   // [kk][256*32]
    __shared__ short Bs[2][4096];   // [kk][128*32]
    const int t = threadIdx.x;
    const int lane = t & 63, wave = t >> 6;       // 0..7
    const int wr = wave >> 1, wc = wave & 1;      // 4x2 waves, each 64x64
    const int nbn = N >> 7;
    const int cpx = gridDim.x >> 3;
    const int swz = (blockIdx.x & 7) * cpx + (blockIdx.x >> 3);
    const int bm = swz / nbn, bn = swz % nbn;
    const int m0 = bm*256, n0 = bn*128;
    const int l15 = lane & 15, lhi = lane >> 4;

    f32x4 acc[4][4];
    #pragma unroll
    for (int i=0;i<4;i++)
        #pragma unroll
        for (int j=0;j<4;j++) acc[i][j] = (f32x4){0.f,0.f,0.f,0.f};

    for (int k0 = 0; k0 < K; k0 += 64) {
        #pragma unroll
        for (int kk = 0; kk < 2; ++kk) {
            #pragma unroll
            for (int it = 0; it < 2; ++it) {       // A: 256x32 = 512 thr x 2 chunks
                int base = (it*512 + wave*64)*8;
                int off  = base + lane*8;
                int row = off >> 5, col = off & 31;
                __builtin_amdgcn_global_load_lds(
                    (const __attribute__((address_space(1))) void*)(A + (size_t)(m0+row)*K + k0 + kk*32 + col),
                    (__attribute__((address_space(3))) void*)(&As[kk][base]), 16, 0, 0);
            }
            {                                      // B: 128x32 = 512 thr x 1 chunk
                int base = (wave*64)*8;
                int off  = base + lane*8;
                int row = off >> 5, col = off & 31;
                __builtin_amdgcn_global_load_lds(
                    (const __attribute__((address_space(1))) void*)(Bt + (size_t)(n0+row)*K + k0 + kk*32 + col),
                    (__attribute__((address_space(3))) void*)(&Bs[kk][base]), 16, 0, 0);
            }
        }
        __syncthreads();
        #pragma unroll
        for (int kk = 0; kk < 2; ++kk) {
            bf16x8 a[4], b[4];
            #pragma unroll
            for (int i=0;i<4;i++)
                a[i] = *(const bf16x8*)&As[kk][(wr*64 + i*16 + l15)*32 + lhi*8];
            #pragma unroll
            for (int j=0;j<4;j++)
                b[j] = *(const bf16x8*)&Bs[kk][(wc*64 + j*16 + l15)*32 + lhi*8];
            #pragma unroll
            for (int i=0;i<4;i++)
                #pragma unroll
                for (int j=0;j<4;j++)
                    acc[i][j] = MFMA16(a[i], b[j], acc[i][j]);
        }
        __syncthreads();
    }

    #pragma unroll
    for (int i=0;i<4;i++)
        #pragma unroll
        for (int j=0;j<4;j++)
            #pragma unroll
            for (int jj=0;jj<4;jj++) {
                int row = m0 + wr*64 + i*16 + lhi*4 + jj;
                int col = n0 + wc*64 + j*16 + l15;
                Cout[(size_t)row*N + col] = cv1(acc[i][j][jj]);
            }
}

// ---------------- out-projection GEMM with FUSED combine in A-staging ----------------
__global__ __launch_bounds__(256) void gemm_out(const short* __restrict__ obuf,
        const float* __restrict__ lbuf, const short* __restrict__ Bt,
        float* __restrict__ Cout)
{
    const int N = 1024, K = 1024;
    __shared__ short As[2*128*32];
    __shared__ short Bs[2*128*32];
    const int t = threadIdx.x;
    const int lane = t & 63, wave = t >> 6;
    const int wr = wave >> 1, wc = wave & 1;
    const int nbn = 8;
    const int cpx = gridDim.x >> 3;
    const int swz = (blockIdx.x & 7) * cpx + (blockIdx.x >> 3);
    const int bm = swz / nbn, bn = swz % nbn;
    const int m0 = bm*128, n0 = bn*128;
    const int l15 = lane & 15, lhi = lane >> 4;

    f32x4 acc[4][4];
    #pragma unroll
    for (int i=0;i<4;i++)
        #pragma unroll
        for (int j=0;j<4;j++) acc[i][j] = (f32x4){0.f,0.f,0.f,0.f};

    for (int k0 = 0; k0 < K; k0 += 64) {
        #pragma unroll
        for (int kk = 0; kk < 2; ++kk) {
            #pragma unroll
            for (int it = 0; it < 2; ++it) {
                const int loff = (it*256 + wave*64 + lane)*8;
                const int row = loff >> 5, col = loff & 31;
                const int grow = m0 + row;
                const int gcol = k0 + kk*32 + col;
                const int bq = grow >> 11, q = grow & 2047;
                const int h = gcol >> 6, d = gcol & 63;
                const size_t tile = ((size_t)(bq*16 + h) << 6) + (q >> 5);
                const short* op = obuf + tile*4096 + (q & 31)*64 + d;
                bf16x8 a0 = *(const bf16x8*)op;
                bf16x8 a1 = *(const bf16x8*)(op + 2048);
                const float* lb = lbuf + tile*64 + (q & 31);
                float inv = 1.0f / (lb[0] + lb[32]);
                unsigned w[4];
                #pragma unroll
                for (int j=0;j<4;j++)
                    w[j] = cvt_pk_bf16((bf2f(a0[2*j])   + bf2f(a1[2*j]))   * inv,
                                       (bf2f(a0[2*j+1]) + bf2f(a1[2*j+1])) * inv);
                __builtin_memcpy(&As[kk*4096 + loff], w, 16);

                const int base = kk*4096 + (it*256 + wave*64)*8;
                __builtin_amdgcn_global_load_lds(
                    (const __attribute__((address_space(1))) void*)(Bt + (size_t)(n0+row)*K + gcol),
                    (__attribute__((address_space(3))) void*)(Bs + base), 16, 0, 0);
            }
        }
        __syncthreads();
        #pragma unroll
        for (int kk = 0; kk < 2; ++kk) {
            bf16x8 a[4], b[4];
            #pragma unroll
            for (int i=0;i<4;i++)
                a[i] = *(const bf16x8*)&As[kk*4096 + (wr*64 + i*16 + l15)*32 + lhi*8];
            #pragma unroll
            for (int j=0;j<4;j++)
                b[j] = *(const bf16x8*)&Bs[kk*4096 + (wc*64 + j*16 + l15)*32 + lhi*8];
            #pragma unroll
            for (int i=0;i<4;i++)
                #pragma unroll
                for (int j=0;j<4;j++)
                    acc[i][j] = MFMA16(a[i], b[j], acc[i][j]);
        }
        __syncthreads();
    }

    #pragma unroll
    for (int i=0;i<4;i++)
        #pragma unroll
        for (int j=0;j<4;j++)
            #pragma unroll
            for (int jj=0;jj<4;jj++) {
                int row = m0 + wr*64 + i*16 + lhi*4 + jj;
                int col = n0 + wc*64 + j*16 + l15;
                Cout[(size_t)row*N + col] = acc[i][j][jj];
            }
}

// ---------------- RoPE + scatter into MFMA-fragment-packed layouts ----------------
__global__ __launch_bounds__(256) void rope_scatter(const short* __restrict__ qkvb,
                             short* __restrict__ qp, short* __restrict__ kp,
                             short* __restrict__ vp,
                             float* __restrict__ kout, float* __restrict__ vout)
{
    __shared__ short vt[64*72];
    const int t = threadIdx.x;
    const int bh = blockIdx.x >> 5;
    const int sb = blockIdx.x & 31;
    const int b = bh >> 4, h = bh & 15;
    const int s_loc = t >> 2, ic = (t & 3) << 3;
    const int s = (sb << 6) + s_loc;
    const size_t rowbase = ((size_t)(b*SEQ + s))*NQKV + h*HD;

    bf16x8 q1 = *(const bf16x8*)&qkvb[rowbase + ic];
    bf16x8 q2 = *(const bf16x8*)&qkvb[rowbase + ic + 32];
    bf16x8 k1 = *(const bf16x8*)&qkvb[rowbase + DIM + ic];
    bf16x8 k2 = *(const bf16x8*)&qkvb[rowbase + DIM + ic + 32];
    bf16x8 v1 = *(const bf16x8*)&qkvb[rowbase + 2*DIM + ic];
    bf16x8 v2 = *(const bf16x8*)&qkvb[rowbase + 2*DIM + ic + 32];

    const float QS = 0.125f * 1.4426950408889634f;
    float q1s[8], q2s[8], k1f[8], k2f[8], v1f[8], v2f[8];
    #pragma unroll
    for (int j=0;j<8;j++){
        int i = ic + j;
        float inv = exp2f(-(float)i * (13.287712379549449f/32.0f));
        float ang = (float)s * inv;
        float sn, cs;
        sincosf(ang, &sn, &cs);
        float q1f = bf2f(q1[j]), q2f = bf2f(q2[j]);
        float ka = bf2f(k1[j]), kb_ = bf2f(k2[j]);
        float qr1 = q1f*cs - q2f*sn, qr2 = q2f*cs + q1f*sn;
        float kr1 = ka*cs - kb_*sn,  kr2 = kb_*cs + ka*sn;
        q1s[j] = qr1*QS; q2s[j] = qr2*QS;
        k1f[j] = kr1; k2f[j] = kr2;
        v1f[j] = bf2f(v1[j]); v2f[j] = bf2f(v2[j]);
    }
    bf16x8 qo1, qo2, ko1, ko2;
    {
        unsigned w[4];
        #pragma unroll
        for (int j=0;j<4;j++) w[j] = cvt_pk_bf16(q1s[2*j], q1s[2*j+1]);
        __builtin_memcpy(&qo1, w, 16);
        #pragma unroll
        for (int j=0;j<4;j++) w[j] = cvt_pk_bf16(q2s[2*j], q2s[2*j+1]);
        __builtin_memcpy(&qo2, w, 16);
        #pragma unroll
        for (int j=0;j<4;j++) w[j] = cvt_pk_bf16(k1f[2*j], k1f[2*j+1]);
        __builtin_memcpy(&ko1, w, 16);
        #pragma unroll
        for (int j=0;j<4;j++) w[j] = cvt_pk_bf16(k2f[2*j], k2f[2*j+1]);
        __builtin_memcpy(&ko2, w, 16);
    }

    const size_t obase = ((size_t)bh*SEQ + s)*HD;
    #pragma unroll
    for (int j4=0;j4<2;j4++){
        *(f32x4*)&kout[obase+ic+j4*4]    = (f32x4){k1f[j4*4],k1f[j4*4+1],k1f[j4*4+2],k1f[j4*4+3]};
        *(f32x4*)&kout[obase+ic+32+j4*4] = (f32x4){k2f[j4*4],k2f[j4*4+1],k2f[j4*4+2],k2f[j4*4+3]};
        *(f32x4*)&vout[obase+ic+j4*4]    = (f32x4){v1f[j4*4],v1f[j4*4+1],v1f[j4*4+2],v1f[j4*4+3]};
        *(f32x4*)&vout[obase+ic+32+j4*4] = (f32x4){v2f[j4*4],v2f[j4*4+1],v2f[j4*4+2],v2f[j4*4+3]};
    }

    {
        const int tkv = (sb << 1) + (s_loc >> 5);
        const int rlo = s_loc & 31;
        const int g1 = ic >> 3,   i1 = g1 >> 1, H1 = g1 & 1;
        const int g2 = 4+(ic>>3), i2 = g2 >> 1, H2 = g2 & 1;
        const size_t tb = ((size_t)bh*64 + tkv)*4;
        *(bf16x8*)&qp[(tb + i1)*512 + (H1*32 + rlo)*8] = qo1;
        *(bf16x8*)&qp[(tb + i2)*512 + (H2*32 + rlo)*8] = qo2;
        *(bf16x8*)&kp[(tb + i1)*512 + (H1*32 + rlo)*8] = ko1;
        *(bf16x8*)&kp[(tb + i2)*512 + (H2*32 + rlo)*8] = ko2;
    }

    #pragma unroll
    for (int j=0;j<8;j++){
        int i = ic + j;
        vt[i*72 + ((((s_loc>>3) ^ (i&7) ^ (i>>3)) & 7)<<3) + (s_loc&7)] = v1[j];
        int i2 = i + 32;
        vt[i2*72 + ((((s_loc>>3) ^ (i2&7) ^ (i2>>3)) & 7)<<3) + (s_loc&7)] = v2[j];
    }
    __syncthreads();

    const int i_out = t >> 2, g = t & 3;
    const int nn = i_out >> 5, l31v = i_out & 31;
    #pragma unroll
    for (int cc=0; cc<2; ++cc){
        int c = 2*g + cc;
        bf16x8 rv = *(const bf16x8*)&vt[i_out*72 + ((((c) ^ (i_out&7) ^ (i_out>>3)) & 7)<<3)];
        int tkv = (sb << 1) + (c >> 2);
        int m = (c >> 1) & 1, H = c & 1;
        size_t va = ((((size_t)bh*64 + tkv)*2 + nn)*2 + m)*512 + (H*32 + l31v)*8;
        *(bf16x8*)&vp[va] = rv;
    }
}

// ---------------- flash attention, partial (KV-split across blocks, 32x32 MFMA) ----------------
#define ATT_BODY(KU, KP) do { \
    const unsigned sOff = (unsigned)step << 11; \
    { int npos = step + 1; npos = (npos < hi) ? npos : step; \
      const unsigned pOff = (unsigned)npos << 11; \
      _Pragma("unroll") \
      for (int i=0;i<4;i++) \
          KP[i] = *(const bf16x8*)&kbase[pOff + i*512 + lane*8]; } \
    bf16x8 vf[2][2]; \
    _Pragma("unroll") \
    for (int nn=0;nn<2;nn++) \
        _Pragma("unroll") \
        for (int m=0;m<2;m++) \
            vf[nn][m] = *(const bf16x8*)&vbase[sOff + nn*1024 + m*512 + lane*8]; \
    __builtin_amdgcn_s_setprio(1); \
    f32x16 sacc; \
    _Pragma("unroll") \
    for (int rr=0;rr<16;rr++) sacc[rr] = 0.f; \
    _Pragma("unroll") \
    for (int i=0;i<4;i++) \
        sacc = MFMA32(KU[i], qf[i], sacc); \
    __builtin_amdgcn_s_setprio(0); \
    if (step == n-1) { \
        const int kv0 = step << 5; \
        _Pragma("unroll") \
        for (int rr=0;rr<16;rr++){ \
            int kv = kv0 + (rr&3) + 8*(rr>>2) + 4*H; \
            if (kv > q0 + l31) sacc[rr] = -3.0e38f; \
        } \
    } \
    float p[16]; \
    _Pragma("unroll") \
    for (int rr=0;rr<16;rr++) p[rr] = EXP2(sacc[rr]); \
    unsigned W0 = cvt_pk_bf16(p[0],  p[1]); \
    unsigned W1 = cvt_pk_bf16(p[2],  p[3]); \
    unsigned W2 = cvt_pk_bf16(p[4],  p[5]); \
    unsigned W3 = cvt_pk_bf16(p[6],  p[7]); \
    unsigned W4 = cvt_pk_bf16(p[8],  p[9]); \
    unsigned W5 = cvt_pk_bf16(p[10], p[11]); \
    unsigned W6 = cvt_pk_bf16(p[12], p[13]); \
    unsigned W7 = cvt_pk_bf16(p[14], p[15]); \
    asm("v_permlane32_swap_b32 %0, %1" : "+v"(W0), "+v"(W2)); \
    asm("v_permlane32_swap_b32 %0, %1" : "+v"(W1), "+v"(W3)); \
    asm("v_permlane32_swap_b32 %0, %1" : "+v"(W4), "+v"(W6)); \
    asm("v_permlane32_swap_b32 %0, %1" : "+v"(W5), "+v"(W7)); \
    u32x4 paw0 = (u32x4){W0, W1, W2, W3}; \
    u32x4 paw1 = (u32x4){W4, W5, W6, W7}; \
    bf16x8 pa[2]; \
    __builtin_memcpy(&pa[0], &paw0, 16); \
    __builtin_memcpy(&pa[1], &paw1, 16); \
    __builtin_amdgcn_s_setprio(1); \
    _Pragma("unroll") \
    for (int nn=0;nn<2;nn++) \
        _Pragma("unroll") \
        for (int m=0;m<2;m++) \
            o[nn] = MFMA32(pa[m], vf[nn][m], o[nn]); \
    psum = MFMA32(pa[0], onesf, psum); \
    psum = MFMA32(pa[1], onesf, psum); \
    __builtin_amdgcn_s_setprio(0); \
} while(0)

__global__ __launch_bounds__(64) void attn_partial(
        const short* __restrict__ qp, const short* __restrict__ kp,
        const short* __restrict__ vp, short* __restrict__ obuf,
        float* __restrict__ lbuf)
{
    const int lane = threadIdx.x;
    const int wg = blockIdx.x;               // 4096 = 8x * 8bh-hi * 32pp * 2half
    const int x = wg & 7;                    // XCD swizzle
    const int r = wg >> 3;                   // 0..511
    const int half = r & 1;
    const int pp = (r >> 1) & 31;
    const int bh = (x << 3) | (r >> 6);
    const int l31 = lane & 31;
    const int H = lane >> 5;                 // 0 or 1
    const short* kbase = kp + (size_t)bh * 64 * 2048;
    const short* vbase = vp + (size_t)bh * 64 * 2048;
    const short* qbase = qp + (size_t)bh * 64 * 2048;

    bf16x8 onesf;
    #pragma unroll
    for (int j=0;j<8;j++) onesf[j] = (short)0x3F80;   // bf16 1.0

    #pragma unroll 1
    for (int part = 0; part < 2; ++part) {
        const int qt = part ? (63 - pp) : pp;
        const int q0 = qt << 5;
        const int n  = qt + 1;               // total kv32 steps for this tile
        const int mid = (n + 1) >> 1;
        const int lo = half ? mid : 0;
        const int hi = half ? n : mid;

        bf16x8 qf[4];
        #pragma unroll
        for (int i=0;i<4;i++)
            qf[i] = *(const bf16x8*)&qbase[(unsigned)qt*2048 + i*512 + lane*8];

        f32x16 o[2], psum;
        #pragma unroll
        for (int nn=0;nn<2;nn++)
            #pragma unroll
            for (int rr=0;rr<16;rr++) o[nn][rr] = 0.f;
        #pragma unroll
        for (int rr=0;rr<16;rr++) psum[rr] = 0.f;

        if (lo < hi) {
            bf16x8 kfA[4], kfB[4];
            #pragma unroll
            for (int i=0;i<4;i++)
                kfA[i] = *(const bf16x8*)&kbase[(unsigned)lo*2048 + i*512 + lane*8];

            int step = lo;
            while (1) {
                ATT_BODY(kfA, kfB);
                ++step; if (step >= hi) break;
                ATT_BODY(kfB, kfA);
                ++step; if (step >= hi) break;
            }
        }

        short* ob = obuf + (size_t)(((bh << 6) | qt)*2 + half) * 2048;
        #pragma unroll
        for (int nn=0;nn<2;nn++)
            #pragma unroll
            for (int rr=0;rr<16;rr++){
                int qloc = (rr&3) + 8*(rr>>2) + 4*H;
                ob[qloc*64 + nn*32 + l31] = cv1(o[nn][rr]);
            }
        float* lb = lbuf + (size_t)(((bh << 6) | qt)*2 + half) * 32;
        if (l31 == 0) {
            #pragma unroll
            for (int rr=0;rr<16;rr++){
                int qloc = (rr&3) + 8*(rr>>2) + 4*H;
                lb[qloc] = psum[rr];
            }
        }
    }
}
#undef ATT_BODY

extern "C" void kernel_launch(void* const* d_in, const int* in_sizes, int n_in,
                              void* d_out, int out_size, void* d_ws, size_t ws_size,
                              hipStream_t stream) {
    const float* x     = (const float*)d_in[0];
    const float* w_qkv = (const float*)d_in[1];
    const float* w_out = (const float*)d_in[2];
    float* out  = (float*)d_out;
    float* kout = out + (size_t)BATCH*SEQ*DIM;          // 8388608
    float* vout = kout + (size_t)BH*SEQ*HD;             // +8388608

    char* ws = (char*)d_ws;
    short* xb    = (short*)(ws + 0);                    // 16 MB
    short* wqkvT = (short*)(ws + 16777216);             // 6 MB
    short* woutT = (short*)(ws + 23068672);             // 2 MB
    short* qkvb  = (short*)(ws + 25165824);             // 48 MB (8192x3072 bf16)
    short* obuf  = (short*)(ws + 25165824);             // reuses qkvb after rope
    float* lbuf  = (float*)(ws + 25165824 + 33554432);
    short* qp    = (short*)(ws + 75497472);             // 16 MB (packed Q frags)
    short* kp    = (short*)(ws + 92274688);             // 16 MB (packed K frags)
    short* vp    = (short*)(ws + 109051904);            // 16 MB (packed V frags)

    conv_bf16<<<(BATCH*SEQ*DIM)/1024, 256, 0, stream>>>(x, xb, (BATCH*SEQ*DIM)/4);
    transpose_conv<<<dim3(NQKV/32, DIM/32), dim3(32,8), 0, stream>>>(w_qkv, wqkvT, DIM, NQKV);
    transpose_conv<<<dim3(DIM/32, DIM/32), dim3(32,8), 0, stream>>>(w_out, woutT, DIM, DIM);

    gemm_bt2<<<(8192/256)*(NQKV/128), 512, 0, stream>>>(xb, wqkvT, qkvb, 8192, NQKV, DIM);

    rope_scatter<<<BH*(SEQ/64), 256, 0, stream>>>(qkvb, qp, kp, vp, kout, vout);

    attn_partial<<<4096, 64, 0, stream>>>(qp, kp, vp, obuf, lbuf);

    gemm_out<<<(8192/128)*(DIM/128), 256, 0, stream>>>(obuf, lbuf, woutT, out);
}